// Round 11
// baseline (146.811 us; speedup 1.0000x reference)
//
#include <hip/hip_runtime.h>

// ChoopyLoss: loss = -(1/B) * sum_{i,j} out[i,j] * r[i,j]
// where r[i,j] = 2*cum[i,j] / (j+1 + total_i)   (exact simplification of F1)
// B=2048, N=8192.
//
// R10 post-mortem: 4 structurally different kernels all ~43us. VGPR counts
// (28/48/56) prove hipcc dissolves source-level double-buffers and emits
// serial load->use chains (MLP~1/wave). Fix: inline-asm global_load_dwordx4
// (cannot be sunk) + counted s_waitcnt vmcnt(N) waits that tie the buffer
// registers as "+v" operands (uses cannot be hoisted above the wait).
// Wave-per-row, no LDS, no barriers. 8-16 loads in flight per wave.

#define NROW 8192
#define WAVES_PER_BLOCK 4
#define BLOCK (64 * WAVES_PER_BLOCK)
#define NCHUNK 32          // 8192 / (64 lanes * 4 elems)
#define GRP 8              // chunks per pipeline group
#define NGRP (NCHUNK / GRP)

using i32x4 = __attribute__((ext_vector_type(4))) int;
using f32x4 = __attribute__((ext_vector_type(4))) float;

// Issue a 16B load the compiler cannot sink or dissolve.
#define GLOAD(dst, p) \
    asm volatile("global_load_dwordx4 %0, %1, off" : "=v"(dst) : "v"(p))

// Wait until at most N vector-memory ops are outstanding; ties all 8 buffer
// registers through the asm so no use can be scheduled above the wait.
#define WAITTIE(N, b) \
    asm volatile("s_waitcnt vmcnt(" #N ")" \
        : "+v"((b)[0]), "+v"((b)[1]), "+v"((b)[2]), "+v"((b)[3]), \
          "+v"((b)[4]), "+v"((b)[5]), "+v"((b)[6]), "+v"((b)[7]))

__device__ __forceinline__ int mbcnt64(unsigned long long m) {
    return __builtin_amdgcn_mbcnt_hi((unsigned)(m >> 32),
           __builtin_amdgcn_mbcnt_lo((unsigned)m, 0u));
}

__global__ __launch_bounds__(BLOCK) void f1_row_kernel(
    const float* __restrict__ outv,
    const int* __restrict__ labels,
    float* __restrict__ partials)
{
    const int t    = threadIdx.x;
    const int lane = t & 63;
    const int wid  = t >> 6;
    const int row  = blockIdx.x * WAVES_PER_BLOCK + wid;

    const long long rowbase = (long long)row * NROW;
    const int*   labp = labels + rowbase;
    const float* outp = outv  + rowbase;

    i32x4 LA[GRP], LB[GRP];
    f32x4 FA[GRP], FB[GRP];

    // ---------------- PASS 1: stream labels, stash bits, per-lane count ----
    unsigned long long mlo = 0ull, mhi = 0ull;  // 4 bits per chunk
    int cnt = 0;                                 // per-lane label count

    #pragma unroll
    for (int i = 0; i < GRP; ++i) GLOAD(LA[i], labp + (i * 64 + lane) * 4);

    #pragma unroll
    for (int g = 0; g < NGRP; ++g) {
        if (g + 1 < NGRP) {
            #pragma unroll
            for (int i = 0; i < GRP; ++i) {
                const int* p = labp + (((g + 1) * GRP + i) * 64 + lane) * 4;
                if (g & 1) { GLOAD(LA[i], p); } else { GLOAD(LB[i], p); }
            }
        } else {
            // bridge the pass boundary: issue first out-group loads now
            #pragma unroll
            for (int i = 0; i < GRP; ++i)
                GLOAD(FA[i], outp + (i * 64 + lane) * 4);
        }
        if (g & 1) { WAITTIE(8, LB); } else { WAITTIE(8, LA); }
        #pragma unroll
        for (int i = 0; i < GRP; ++i) {
            const i32x4 lv = (g & 1) ? LB[i] : LA[i];
            const int c = g * GRP + i;
            const unsigned b0 = (lv[0] != 0), b1 = (lv[1] != 0),
                           b2 = (lv[2] != 0), b3 = (lv[3] != 0);
            cnt += (int)(b0 + b1 + b2 + b3);
            const unsigned long long nib =
                (unsigned long long)(b0 | (b1 << 1) | (b2 << 2) | (b3 << 3));
            if (c < 16) mlo |= nib << (c * 4); else mhi |= nib << ((c - 16) * 4);
        }
    }

    // wave-wide row total (6 xor-shuffles)
    #pragma unroll
    for (int off = 1; off < 64; off <<= 1) cnt += __shfl_xor(cnt, off, 64);
    const float ftot = (float)cnt;   // total==0 fine: cum==0 -> every term 0

    // ---------------- PASS 2: stream out, weighted accumulate ---------------
    float acc = 0.f;
    int runbase = 0;
    #pragma unroll
    for (int g = 0; g < NGRP; ++g) {
        if (g + 1 < NGRP) {
            #pragma unroll
            for (int i = 0; i < GRP; ++i) {
                const float* p = outp + (((g + 1) * GRP + i) * 64 + lane) * 4;
                if (g & 1) { GLOAD(FA[i], p); } else { GLOAD(FB[i], p); }
            }
            if (g & 1) { WAITTIE(8, FB); } else { WAITTIE(8, FA); }
        } else {
            if (g & 1) { WAITTIE(0, FB); } else { WAITTIE(0, FA); }
        }
        #pragma unroll
        for (int i = 0; i < GRP; ++i) {
            const f32x4 ov = (g & 1) ? FB[i] : FA[i];
            const int c = g * GRP + i;
            const unsigned nib = (unsigned)(((c < 16) ? (mlo >> (c * 4))
                                                      : (mhi >> ((c - 16) * 4))) & 0xFull);
            const int b0 = nib & 1, b1 = (nib >> 1) & 1,
                      b2 = (nib >> 2) & 1, b3 = (nib >> 3) & 1;
            const unsigned long long m0 = __ballot(b0), m1 = __ballot(b1),
                                     m2 = __ballot(b2), m3 = __ballot(b3);
            int cum = runbase + mbcnt64(m0) + mbcnt64(m1) + mbcnt64(m2) + mbcnt64(m3);
            const int kbase = c * 256 + lane * 4;   // k = kbase + e + 1
            cum += b0;
            acc = fmaf(ov[0], (float)(2 * cum) * __builtin_amdgcn_rcpf((float)(kbase + 1) + ftot), acc);
            cum += b1;
            acc = fmaf(ov[1], (float)(2 * cum) * __builtin_amdgcn_rcpf((float)(kbase + 2) + ftot), acc);
            cum += b2;
            acc = fmaf(ov[2], (float)(2 * cum) * __builtin_amdgcn_rcpf((float)(kbase + 3) + ftot), acc);
            cum += b3;
            acc = fmaf(ov[3], (float)(2 * cum) * __builtin_amdgcn_rcpf((float)(kbase + 4) + ftot), acc);
            runbase += __popcll(m0) + __popcll(m1) + __popcll(m2) + __popcll(m3);
        }
    }

    // ---------------- wave-internal reduction, one write per row ------------
    #pragma unroll
    for (int off = 32; off > 0; off >>= 1) acc += __shfl_down(acc, off, 64);
    if (lane == 0) partials[row] = acc;
}

__global__ __launch_bounds__(256) void f1_finalize_kernel(
    const float* __restrict__ partials, float* __restrict__ out, int B)
{
    double s = 0.0;
    for (int i = threadIdx.x; i < B; i += 256) s += (double)partials[i];
    #pragma unroll
    for (int off = 32; off > 0; off >>= 1) s += __shfl_down(s, off, 64);
    __shared__ double ws[4];
    const int lane = threadIdx.x & 63, wid = threadIdx.x >> 6;
    if (lane == 0) ws[wid] = s;
    __syncthreads();
    if (threadIdx.x == 0) {
        out[0] = (float)(-(ws[0] + ws[1] + ws[2] + ws[3]) / (double)B);
    }
}

extern "C" void kernel_launch(void* const* d_in, const int* in_sizes, int n_in,
                              void* d_out, int out_size, void* d_ws, size_t ws_size,
                              hipStream_t stream) {
    const float* outv   = (const float*)d_in[0];   // [B, N, 1] f32
    const int*   labels = (const int*)d_in[1];     // [B, N] i32
    float* partials = (float*)d_ws;                // B floats of scratch
    float* result   = (float*)d_out;

    const int B = 2048;
    f1_row_kernel<<<B / WAVES_PER_BLOCK, BLOCK, 0, stream>>>(outv, labels, partials);
    f1_finalize_kernel<<<1, 256, 0, stream>>>(partials, result, B);
}